// Round 26
// baseline (230.410 us; speedup 1.0000x reference)
//
#include <hip/hip_runtime.h>
#include <stdint.h>

typedef uint32_t u32;
typedef __attribute__((ext_vector_type(4))) float f32x4;
typedef __attribute__((ext_vector_type(8))) short short8;

#define NBATCH 16
#define NPIX   16384      // H*W
#define NPB    1048576    // per-batch flat elems (C*H*W = 1024*1024)

__device__ __forceinline__ ushort f2bf(float f) {
  u32 b = __builtin_bit_cast(u32, f);
  return (ushort)((b + 0x7FFFu + ((b >> 16) & 1u)) >> 16);
}
__device__ __forceinline__ float bf2f(ushort h) {
  return __builtin_bit_cast(float, (u32)h << 16);
}

// async global->LDS, 16B per lane. LDS dest must be wave-uniform base;
// HW scatters lane i at base + i*16. Global source is per-lane.
__device__ __forceinline__ void gload16(const void* g, void* l) {
  __builtin_amdgcn_global_load_lds(
      (const __attribute__((address_space(1))) u32*)g,
      (__attribute__((address_space(3))) u32*)l,
      16, 0, 0);
}

// ---------------- Kernel 0: pack weights for MFMA-proj -----------------------
__global__ void prep_w2(const float* __restrict__ Wq, const float* __restrict__ bq,
                        const float* __restrict__ Wk, const float* __restrict__ bk,
                        const float* __restrict__ Wv, const float* __restrict__ bv,
                        ushort* __restrict__ Wpk, float* __restrict__ bpk)
{
  int gid = blockIdx.x * 256 + threadIdx.x;
  if (gid < 12288) {
    int m = gid >> 7, kk = gid & 127;
    int ch = kk & 63;
    ushort outv = 0;
    if (m < 8) {
      float wv = Wq[m * 64 + ch];
      ushort h = f2bf(wv);
      outv = (kk < 64) ? h : f2bf(wv - bf2f(h));
    } else if (m < 16) {
      float wv = Wk[(m - 8) * 64 + ch];
      ushort h = f2bf(wv);
      outv = (kk < 64) ? h : f2bf(wv - bf2f(h));
    } else if (m < 80) {
      outv = (kk < 64) ? f2bf(Wv[(m - 16) * 64 + ch]) : (ushort)0;
    }
    Wpk[gid] = outv;
  } else if (gid < 12368) {
    int o = gid - 12288;
    bpk[o] = (o < 8) ? bq[o] : (o < 16 ? bk[o - 8] : bv[o - 16]);
  }
}

// ---------------- Kernel 1: MFMA proj, 512 threads (16 waves/CU) -------------
// proj12 structure at 8 waves/block: wave w owns ONE 16-px N-tile (px =
// w*16+l15). Staging map unchanged (4 slots/thread/chunk -> vmcnt(4)).
// Epilogue verified: t<128 Q/K, t in [128,256) V.
__global__ __launch_bounds__(512) void proj13(
    const float* __restrict__ x, const ushort* __restrict__ Wpk,
    const float* __restrict__ bpk,
    ushort* __restrict__ Qt2, ushort* __restrict__ Kt2,
    ushort* __restrict__ Vt)
{
  __shared__ __align__(16) char smem[65536];
  int t = threadIdx.x;
  int w = t >> 6, lane = t & 63;
  int l15 = lane & 15, l4 = lane >> 4;

  int g = blockIdx.x;
  int lin = (g & 7) * 128 + (g >> 3);
  int b = lin >> 6;
  int l0 = (lin & 63) << 4;     // 16 l per block; chunks at l0, l0+8

  const uint4* Wp4 = (const uint4*)Wpk;   // row stride 16 uint4
  uint4 Afrag[12];
  #pragma unroll
  for (int kc = 0; kc < 4; ++kc)
    Afrag[kc] = Wp4[l15 * 16 + kc * 4 + l4];
  #pragma unroll
  for (int mt = 1; mt < 5; ++mt)
    #pragma unroll
    for (int kc = 0; kc < 2; ++kc)
      Afrag[2 + mt * 2 + kc] = Wp4[(mt * 16 + l15) * 16 + kc * 4 + l4];
  __builtin_amdgcn_sched_barrier(0);

  #pragma unroll
  for (int c = 0; c < 2; ++c) {
    const float* xb = x + (size_t)b * NPB + l0 + c * 8;
    float* xs = (float*)(smem + c * 32768);
    #pragma unroll
    for (int it = 0; it < 4; ++it) {
      int f0 = (it * 8 + w) * 64;
      int f = f0 + lane;
      int ch = f >> 5, r2 = f & 31, tc = r2 >> 1, half = r2 & 1;
      gload16(xb + (size_t)ch * NPIX + tc * 1024 + half * 4, xs + f0 * 4);
    }
  }
  asm volatile("s_waitcnt vmcnt(4)" ::: "memory");   // chunk0 + Afrags landed
  __builtin_amdgcn_sched_barrier(0);
  __builtin_amdgcn_s_barrier();

  auto do_chunk = [&](char* region, int lc) {
    float* xs = (float*)region;
    f32x4 acc[5];
    #pragma unroll
    for (int mt = 0; mt < 5; ++mt) {
      f32x4 bv4;
      #pragma unroll
      for (int r = 0; r < 4; ++r) bv4[r] = bpk[mt * 16 + l4 * 4 + r];
      acc[mt] = bv4;
    }
    {
      int px = w * 16 + l15;
      u32 xr[16];
      #pragma unroll
      for (int kc = 0; kc < 2; ++kc)
        #pragma unroll
        for (int j = 0; j < 8; ++j)
          xr[kc * 8 + j] = ((const u32*)xs)[(kc * 32 + l4 * 8 + j) * 128 + px];
      uint4 bxh[2], bxl[2];
      #pragma unroll
      for (int kc = 0; kc < 2; ++kc)
        #pragma unroll
        for (int p = 0; p < 4; ++p) {
          u32 a = xr[kc * 8 + 2 * p], cc = xr[kc * 8 + 2 * p + 1];
          ((u32*)&bxh[kc])[p] = (a >> 16) | (cc & 0xFFFF0000u);
          float fa = __builtin_bit_cast(float, a) -
                     __builtin_bit_cast(float, a & 0xFFFF0000u);
          float fc = __builtin_bit_cast(float, cc) -
                     __builtin_bit_cast(float, cc & 0xFFFF0000u);
          u32 la = __builtin_bit_cast(u32, fa), lc2 = __builtin_bit_cast(u32, fc);
          ((u32*)&bxl[kc])[p] = (la >> 16) | (lc2 & 0xFFFF0000u);
        }
      short8 h0 = __builtin_bit_cast(short8, bxh[0]);
      short8 h1 = __builtin_bit_cast(short8, bxh[1]);
      short8 s0 = __builtin_bit_cast(short8, bxl[0]);
      short8 s1 = __builtin_bit_cast(short8, bxl[1]);
      acc[0] = __builtin_amdgcn_mfma_f32_16x16x32_bf16(
          __builtin_bit_cast(short8, Afrag[0]), h0, acc[0], 0, 0, 0);
      acc[0] = __builtin_amdgcn_mfma_f32_16x16x32_bf16(
          __builtin_bit_cast(short8, Afrag[1]), h1, acc[0], 0, 0, 0);
      acc[0] = __builtin_amdgcn_mfma_f32_16x16x32_bf16(
          __builtin_bit_cast(short8, Afrag[0]), s0, acc[0], 0, 0, 0);
      acc[0] = __builtin_amdgcn_mfma_f32_16x16x32_bf16(
          __builtin_bit_cast(short8, Afrag[1]), s1, acc[0], 0, 0, 0);
      acc[0] = __builtin_amdgcn_mfma_f32_16x16x32_bf16(
          __builtin_bit_cast(short8, Afrag[2]), h0, acc[0], 0, 0, 0);
      acc[0] = __builtin_amdgcn_mfma_f32_16x16x32_bf16(
          __builtin_bit_cast(short8, Afrag[3]), h1, acc[0], 0, 0, 0);
      #pragma unroll
      for (int mt = 1; mt < 5; ++mt) {
        acc[mt] = __builtin_amdgcn_mfma_f32_16x16x32_bf16(
            __builtin_bit_cast(short8, Afrag[2 + mt * 2]), h0, acc[mt], 0, 0, 0);
        acc[mt] = __builtin_amdgcn_mfma_f32_16x16x32_bf16(
            __builtin_bit_cast(short8, Afrag[3 + mt * 2]), h1, acc[mt], 0, 0, 0);
      }
    }
    __syncthreads();   // all xs reads done before epilogue overwrites region

    float*  qkl = (float*)region;                    // [16][132]
    ushort* vl  = (ushort*)(region + 16 * 132 * 4);  // [64][136]
    {
      int px = w * 16 + l15;
      #pragma unroll
      for (int r = 0; r < 4; ++r)
        qkl[(l4 * 4 + r) * 132 + px] = acc[0][r];
      #pragma unroll
      for (int mt = 1; mt < 5; ++mt)
        #pragma unroll
        for (int r = 0; r < 4; ++r)
          vl[((mt - 1) * 16 + l4 * 4 + r) * 136 + px] = f2bf(acc[mt][r]);
    }
    __syncthreads();

    if (t < 128) {
      // Q/K split bf16 (verified): Q=[qh][ql], K=[kh][kl], stride 256.
      int l = t >> 4, tcc = t & 15;
      size_t lrow = (size_t)b * 1024 + lc + l;
      int px = tcc * 8 + l;

      union { ushort s[8]; uint4 v; } qh, ql, kh, kl;
      #pragma unroll
      for (int o = 0; o < 8; ++o) {
        float qv = qkl[o * 132 + px];
        ushort h = f2bf(qv);
        qh.s[o] = h; ql.s[o] = f2bf(qv - bf2f(h));
        float kv = qkl[(8 + o) * 132 + px];
        h = f2bf(kv);
        kh.s[o] = h; kl.s[o] = f2bf(kv - bf2f(h));
      }
      ushort* qrow = Qt2 + lrow * 256 + tcc * 8;
      *(uint4*)qrow         = qh.v;
      *(uint4*)(qrow + 128) = ql.v;
      ushort* krow = Kt2 + lrow * 256 + tcc * 8;
      *(uint4*)krow         = kh.v;
      *(uint4*)(krow + 128) = kl.v;
    } else if (t < 256) {
      // V rows (verified path), concurrent with Q/K.
      int t2 = t - 128;
      int l = t2 >> 4, tcc = t2 & 15;
      size_t lrow = (size_t)b * 1024 + lc + l;

      ushort* vrow = Vt + lrow * 1024;
      #pragma unroll
      for (int it = 0; it < 4; ++it) {
        int c2 = (it << 4) + tcc;
        union { ushort s[16]; uint4 q[2]; } ov;
        #pragma unroll
        for (int tt = 0; tt < 16; ++tt)
          ov.s[tt] = vl[c2 * 136 + tt * 8 + l];
        *(uint4*)(vrow + c2 * 16)     = ov.q[0];
        *(uint4*)(vrow + c2 * 16 + 8) = ov.q[1];
      }
    }
  };

  do_chunk(smem, l0);
  do_chunk(smem + 32768, l0 + 8);
}

// ---------------- Kernel 2: gemm1 = S scores, 128x128, 5 blocks/CU -----------
// S[i][j] = qh_i.kh_j + ql_i.kh_j + qh_i.kl_j over 6 (KA,KB) tiles.
// 128^2 tile, 256 threads (2x2 waves), acc[4][4], 32KB single-buffer LDS,
// __syncthreads sync. Maps = verified restrictions (row step 32 == 0 mod 8).
__global__ __launch_bounds__(256, 5) void gemm_qk2(
    const ushort* __restrict__ A,
    const ushort* __restrict__ B,
    float* __restrict__ C)
{
  __shared__ ushort Asm[8192];    // [128][64]
  __shared__ ushort Bsm[8192];    // [128][64]
  int t = threadIdx.x;

  // bijective XCD-chunk remap: 1024 blocks, 128 per XCD = 2 batches
  int g = blockIdx.x;
  int lin = (g & 7) * 128 + (g >> 3);
  int bz = lin >> 6;
  int by = (lin >> 3) & 7;
  int bx = lin & 7;
  int m0 = by << 7, n0 = bx << 7;

  const ushort* Ab = A + (size_t)bz * 1024 * 256;
  const ushort* Bb = B + (size_t)bz * 1024 * 256;
  int w = t >> 6, lane = t & 63;
  int wm = w >> 1, wn = w & 1;
  int l15 = lane & 15, l4 = lane >> 4;

  int swc = (t & 7) ^ ((t >> 3) & 7);
  const ushort* pa = Ab + (size_t)(m0 + (t >> 3)) * 256 + swc * 8;
  const ushort* pb = Bb + (size_t)(n0 + (t >> 3)) * 256 + swc * 8;
  int wb = w * 512;   // wave base within a 4KB staging round (ushorts)

  constexpr int KA[6] = {0, 64, 128, 192, 0, 64};
  constexpr int KB[6] = {0, 64, 0, 64, 128, 192};

  f32x4 acc[4][4] = {};

  for (int it = 0; it < 6; ++it) {
    #pragma unroll
    for (int i = 0; i < 4; ++i)      // A: rows t>>3 + i*32
      gload16(pa + (size_t)i * 32 * 256 + KA[it], Asm + i * 2048 + wb);
    #pragma unroll
    for (int i = 0; i < 4; ++i)      // B: rows t>>3 + i*32
      gload16(pb + (size_t)i * 32 * 256 + KB[it], Bsm + i * 2048 + wb);
    __syncthreads();                 // drain vmcnt + barrier (m97 pattern)

    #pragma unroll
    for (int kk = 0; kk < 2; ++kk) {
      short8 af[4], bfr[4];
      #pragma unroll
      for (int mi = 0; mi < 4; ++mi) {
        int rr = (wm << 6) + (mi << 4) + l15;
        af[mi] = __builtin_bit_cast(short8,
            ((const uint4*)Asm)[rr * 8 + ((kk * 4 + l4) ^ (rr & 7))]);
      }
      #pragma unroll
      for (int ni = 0; ni < 4; ++ni) {
        int rr = (wn << 6) + (ni << 4) + l15;
        bfr[ni] = __builtin_bit_cast(short8,
            ((const uint4*)Bsm)[rr * 8 + ((kk * 4 + l4) ^ (rr & 7))]);
      }
      #pragma unroll
      for (int mi = 0; mi < 4; ++mi)
        #pragma unroll
        for (int ni = 0; ni < 4; ++ni)
          acc[mi][ni] = __builtin_amdgcn_mfma_f32_16x16x32_bf16(
              af[mi], bfr[ni], acc[mi][ni], 0, 0, 0);
    }
    __syncthreads();                 // all reads done before next overwrite
  }

  #pragma unroll
  for (int mi = 0; mi < 4; ++mi) {
    int rbase = m0 + (wm << 6) + (mi << 4) + (l4 << 2);
    #pragma unroll
    for (int ni = 0; ni < 4; ++ni) {
      int col = n0 + (wn << 6) + (ni << 4) + l15;
      f32x4 v = acc[mi][ni];
      #pragma unroll
      for (int rr = 0; rr < 4; ++rr) {
        size_t idx = ((size_t)bz * 1024 + rbase + rr) * 1024 + col;
        C[idx] = v[rr];
      }
    }
  }
}

// ---------------- Kernel 4: gemm2, 128x128, 5 blocks/CU ----------------------
// out = P.Vt^T + X. Same 128^2 structure as gemm_qk2; K=1024 (16 iters).
__global__ __launch_bounds__(256, 5) void gemm_pv(
    const ushort* __restrict__ A, int lda,
    const ushort* __restrict__ B, int ldb,
    float* __restrict__ C, const float* __restrict__ X)
{
  __shared__ ushort Asm[8192];    // [128][64]
  __shared__ ushort Bsm[8192];    // [128][64]
  int t = threadIdx.x;

  // bijective XCD-chunk remap: 1024 blocks, 128 per XCD = 2 batches
  int g = blockIdx.x;
  int lin = (g & 7) * 128 + (g >> 3);
  int bz = lin >> 6;
  int by = (lin >> 3) & 7;
  int bx = lin & 7;
  int m0 = by << 7, n0 = bx << 7;

  const ushort* Ab = A + (size_t)bz * 1024 * lda;
  const ushort* Bb = B + (size_t)bz * 1024 * ldb;
  int w = t >> 6, lane = t & 63;
  int wm = w >> 1, wn = w & 1;
  int l15 = lane & 15, l4 = lane >> 4;

  int swc = (t & 7) ^ ((t >> 3) & 7);
  const ushort* pa = Ab + (size_t)(m0 + (t >> 3)) * lda + swc * 8;
  const ushort* pb = Bb + (size_t)(n0 + (t >> 3)) * ldb + swc * 8;
  int wb = w * 512;

  f32x4 acc[4][4] = {};

  for (int it = 0; it < 16; ++it) {
    int k0 = it * 64;
    #pragma unroll
    for (int i = 0; i < 4; ++i)
      gload16(pa + (size_t)i * 32 * lda + k0, Asm + i * 2048 + wb);
    #pragma unroll
    for (int i = 0; i < 4; ++i)
      gload16(pb + (size_t)i * 32 * ldb + k0, Bsm + i * 2048 + wb);
    __syncthreads();                 // drain vmcnt + barrier (m97 pattern)

    #pragma unroll
    for (int kk = 0; kk < 2; ++kk) {
      short8 af[4], bfr[4];
      #pragma unroll
      for (int mi = 0; mi < 4; ++mi) {
        int rr = (wm << 6) + (mi << 4) + l15;
        af[mi] = __builtin_bit_cast(short8,
            ((const uint4*)Asm)[rr * 8 + ((kk * 4 + l4) ^ (rr & 7))]);
      }
      #pragma unroll
      for (int ni = 0; ni < 4; ++ni) {
        int rr = (wn << 6) + (ni << 4) + l15;
        bfr[ni] = __builtin_bit_cast(short8,
            ((const uint4*)Bsm)[rr * 8 + ((kk * 4 + l4) ^ (rr & 7))]);
      }
      #pragma unroll
      for (int mi = 0; mi < 4; ++mi)
        #pragma unroll
        for (int ni = 0; ni < 4; ++ni)
          acc[mi][ni] = __builtin_amdgcn_mfma_f32_16x16x32_bf16(
              af[mi], bfr[ni], acc[mi][ni], 0, 0, 0);
    }
    __syncthreads();                 // all reads done before next overwrite
  }

  #pragma unroll
  for (int mi = 0; mi < 4; ++mi) {
    int rbase = m0 + (wm << 6) + (mi << 4) + (l4 << 2);
    #pragma unroll
    for (int ni = 0; ni < 4; ++ni) {
      int col = n0 + (wn << 6) + (ni << 4) + l15;
      f32x4 v = acc[mi][ni];
      #pragma unroll
      for (int rr = 0; rr < 4; ++rr) {
        size_t idx = ((size_t)bz * 1024 + rbase + rr) * 1024 + col;
        C[idx] = v[rr] + X[idx];
      }
    }
  }
}

// ---------------- Kernel 3: row softmax, P bf16 in place ---------------------
__global__ __launch_bounds__(256) void softmax_rows(float* __restrict__ S)
{
  size_t rowi = blockIdx.x;
  float* srow = S + rowi * 1024;
  int t = threadIdx.x;
  float4 v = ((const float4*)srow)[t];
  float m = fmaxf(fmaxf(v.x, v.y), fmaxf(v.z, v.w));
  #pragma unroll
  for (int off = 32; off > 0; off >>= 1) m = fmaxf(m, __shfl_xor(m, off));
  __shared__ float red[8];
  int wid = t >> 6, lane = t & 63;
  if (lane == 0) red[wid] = m;
  __syncthreads();
  m = fmaxf(fmaxf(red[0], red[1]), fmaxf(red[2], red[3]));
  float e0 = __expf(v.x - m), e1 = __expf(v.y - m);
  float e2 = __expf(v.z - m), e3 = __expf(v.w - m);
  float s = e0 + e1 + e2 + e3;
  #pragma unroll
  for (int off = 32; off > 0; off >>= 1) s += __shfl_xor(s, off);
  if (lane == 0) red[4 + wid] = s;
  __syncthreads();
  s = red[4] + red[5] + red[6] + red[7];
  float inv = 1.0f / s;
  union { ushort h[4]; uint2 q; } pk;
  pk.h[0] = f2bf(e0 * inv); pk.h[1] = f2bf(e1 * inv);
  pk.h[2] = f2bf(e2 * inv); pk.h[3] = f2bf(e3 * inv);
  ((uint2*)srow)[t] = pk.q;
}

// ---------------- Launch -----------------------------------------------------
extern "C" void kernel_launch(void* const* d_in, const int* in_sizes, int n_in,
                              void* d_out, int out_size, void* d_ws, size_t ws_size,
                              hipStream_t stream) {
  const float* x  = (const float*)d_in[0];
  const float* Wq = (const float*)d_in[1];
  const float* bq = (const float*)d_in[2];
  const float* Wk = (const float*)d_in[3];
  const float* bk = (const float*)d_in[4];
  const float* Wv = (const float*)d_in[5];
  const float* bv = (const float*)d_in[6];
  float* out = (float*)d_out;

  char* wsb = (char*)d_ws;
  ushort* Qt2 = (ushort*)wsb;                          //  8,388,608 B
  ushort* Kt2 = (ushort*)(wsb + 8388608);              //  8,388,608 B
  ushort* Vt  = (ushort*)(wsb + 16777216);             // 33,554,432 B
  float*  S   = (float*)(wsb + 50331648);              // 67,108,864 B
  ushort* Wpk = (ushort*)(wsb + 117440512);            // past S (persistent)
  float*  bpk = (float*)(wsb + 117440512 + 24576);

  prep_w2<<<49, 256, 0, stream>>>(Wq, bq, Wk, bk, Wv, bv, Wpk, bpk);
  proj13<<<1024, 512, 0, stream>>>(x, Wpk, bpk, Qt2, Kt2, Vt);
  gemm_qk2<<<1024, 256, 0, stream>>>(Qt2, Kt2, S);
  softmax_rows<<<16384, 256, 0, stream>>>(S);
  gemm_pv<<<1024, 256, 0, stream>>>((const ushort*)S, 2048, Vt, 1024, out, x);
}

// Round 27
// 124.864 us; speedup vs baseline: 1.8453x; 1.8453x over previous
//
#include <hip/hip_runtime.h>
#include <stdint.h>

typedef uint32_t u32;
typedef __attribute__((ext_vector_type(4))) float f32x4;
typedef __attribute__((ext_vector_type(8))) short short8;

#define NBATCH 16
#define NPIX   16384      // H*W
#define NPB    1048576    // per-batch flat elems (C*H*W = 1024*1024)

__device__ __forceinline__ ushort f2bf(float f) {
  u32 b = __builtin_bit_cast(u32, f);
  return (ushort)((b + 0x7FFFu + ((b >> 16) & 1u)) >> 16);
}
__device__ __forceinline__ float bf2f(ushort h) {
  return __builtin_bit_cast(float, (u32)h << 16);
}

// async global->LDS, 16B per lane. LDS dest must be wave-uniform base;
// HW scatters lane i at base + i*16. Global source is per-lane.
__device__ __forceinline__ void gload16(const void* g, void* l) {
  __builtin_amdgcn_global_load_lds(
      (const __attribute__((address_space(1))) u32*)g,
      (__attribute__((address_space(3))) u32*)l,
      16, 0, 0);
}

// ---------------- Kernel 0: pack weights for MFMA-proj -----------------------
__global__ void prep_w2(const float* __restrict__ Wq, const float* __restrict__ bq,
                        const float* __restrict__ Wk, const float* __restrict__ bk,
                        const float* __restrict__ Wv, const float* __restrict__ bv,
                        ushort* __restrict__ Wpk, float* __restrict__ bpk)
{
  int gid = blockIdx.x * 256 + threadIdx.x;
  if (gid < 12288) {
    int m = gid >> 7, kk = gid & 127;
    int ch = kk & 63;
    ushort outv = 0;
    if (m < 8) {
      float wv = Wq[m * 64 + ch];
      ushort h = f2bf(wv);
      outv = (kk < 64) ? h : f2bf(wv - bf2f(h));
    } else if (m < 16) {
      float wv = Wk[(m - 8) * 64 + ch];
      ushort h = f2bf(wv);
      outv = (kk < 64) ? h : f2bf(wv - bf2f(h));
    } else if (m < 80) {
      outv = (kk < 64) ? f2bf(Wv[(m - 16) * 64 + ch]) : (ushort)0;
    }
    Wpk[gid] = outv;
  } else if (gid < 12368) {
    int o = gid - 12288;
    bpk[o] = (o < 8) ? bq[o] : (o < 16 ? bk[o - 8] : bv[o - 16]);
  }
}

// ---------------- Kernel 1: MFMA proj, 2-chunk self-pipelined ----------------
// R20-best structure; epilogue uses ALL 256 threads: t<128 -> Q/K
// (verified path), t>=128 -> V (verified path, t2 = t-128).
__global__ __launch_bounds__(256) void proj12(
    const float* __restrict__ x, const ushort* __restrict__ Wpk,
    const float* __restrict__ bpk,
    ushort* __restrict__ Qt2, ushort* __restrict__ Kt2,
    ushort* __restrict__ Vt)
{
  __shared__ __align__(16) char smem[65536];
  int t = threadIdx.x;
  int w = t >> 6, lane = t & 63;
  int l15 = lane & 15, l4 = lane >> 4;

  int g = blockIdx.x;
  int lin = (g & 7) * 128 + (g >> 3);
  int b = lin >> 6;
  int l0 = (lin & 63) << 4;     // 16 l per block; chunks at l0, l0+8

  const uint4* Wp4 = (const uint4*)Wpk;   // row stride 16 uint4
  uint4 Afrag[12];
  #pragma unroll
  for (int kc = 0; kc < 4; ++kc)
    Afrag[kc] = Wp4[l15 * 16 + kc * 4 + l4];
  #pragma unroll
  for (int mt = 1; mt < 5; ++mt)
    #pragma unroll
    for (int kc = 0; kc < 2; ++kc)
      Afrag[2 + mt * 2 + kc] = Wp4[(mt * 16 + l15) * 16 + kc * 4 + l4];
  __builtin_amdgcn_sched_barrier(0);

  #pragma unroll
  for (int c = 0; c < 2; ++c) {
    const float* xb = x + (size_t)b * NPB + l0 + c * 8;
    float* xs = (float*)(smem + c * 32768);
    #pragma unroll
    for (int it = 0; it < 8; ++it) {
      int f0 = (it * 4 + w) * 64;
      int f = f0 + lane;
      int ch = f >> 5, r2 = f & 31, tc = r2 >> 1, half = r2 & 1;
      gload16(xb + (size_t)ch * NPIX + tc * 1024 + half * 4, xs + f0 * 4);
    }
  }
  asm volatile("s_waitcnt vmcnt(8)" ::: "memory");
  __builtin_amdgcn_sched_barrier(0);
  __builtin_amdgcn_s_barrier();

  auto do_chunk = [&](char* region, int lc) {
    float* xs = (float*)region;
    f32x4 acc[5][2];
    #pragma unroll
    for (int mt = 0; mt < 5; ++mt) {
      f32x4 bv4;
      #pragma unroll
      for (int r = 0; r < 4; ++r) bv4[r] = bpk[mt * 16 + l4 * 4 + r];
      acc[mt][0] = bv4; acc[mt][1] = bv4;
    }
    #pragma unroll
    for (int i = 0; i < 2; ++i) {
      int px = (w * 2 + i) * 16 + l15;
      u32 xr[16];
      #pragma unroll
      for (int kc = 0; kc < 2; ++kc)
        #pragma unroll
        for (int j = 0; j < 8; ++j)
          xr[kc * 8 + j] = ((const u32*)xs)[(kc * 32 + l4 * 8 + j) * 128 + px];
      uint4 bxh[2], bxl[2];
      #pragma unroll
      for (int kc = 0; kc < 2; ++kc)
        #pragma unroll
        for (int p = 0; p < 4; ++p) {
          u32 a = xr[kc * 8 + 2 * p], cc = xr[kc * 8 + 2 * p + 1];
          ((u32*)&bxh[kc])[p] = (a >> 16) | (cc & 0xFFFF0000u);
          float fa = __builtin_bit_cast(float, a) -
                     __builtin_bit_cast(float, a & 0xFFFF0000u);
          float fc = __builtin_bit_cast(float, cc) -
                     __builtin_bit_cast(float, cc & 0xFFFF0000u);
          u32 la = __builtin_bit_cast(u32, fa), lc2 = __builtin_bit_cast(u32, fc);
          ((u32*)&bxl[kc])[p] = (la >> 16) | (lc2 & 0xFFFF0000u);
        }
      short8 h0 = __builtin_bit_cast(short8, bxh[0]);
      short8 h1 = __builtin_bit_cast(short8, bxh[1]);
      short8 s0 = __builtin_bit_cast(short8, bxl[0]);
      short8 s1 = __builtin_bit_cast(short8, bxl[1]);
      acc[0][i] = __builtin_amdgcn_mfma_f32_16x16x32_bf16(
          __builtin_bit_cast(short8, Afrag[0]), h0, acc[0][i], 0, 0, 0);
      acc[0][i] = __builtin_amdgcn_mfma_f32_16x16x32_bf16(
          __builtin_bit_cast(short8, Afrag[1]), h1, acc[0][i], 0, 0, 0);
      acc[0][i] = __builtin_amdgcn_mfma_f32_16x16x32_bf16(
          __builtin_bit_cast(short8, Afrag[0]), s0, acc[0][i], 0, 0, 0);
      acc[0][i] = __builtin_amdgcn_mfma_f32_16x16x32_bf16(
          __builtin_bit_cast(short8, Afrag[1]), s1, acc[0][i], 0, 0, 0);
      acc[0][i] = __builtin_amdgcn_mfma_f32_16x16x32_bf16(
          __builtin_bit_cast(short8, Afrag[2]), h0, acc[0][i], 0, 0, 0);
      acc[0][i] = __builtin_amdgcn_mfma_f32_16x16x32_bf16(
          __builtin_bit_cast(short8, Afrag[3]), h1, acc[0][i], 0, 0, 0);
      #pragma unroll
      for (int mt = 1; mt < 5; ++mt) {
        acc[mt][i] = __builtin_amdgcn_mfma_f32_16x16x32_bf16(
            __builtin_bit_cast(short8, Afrag[2 + mt * 2]), h0, acc[mt][i], 0, 0, 0);
        acc[mt][i] = __builtin_amdgcn_mfma_f32_16x16x32_bf16(
            __builtin_bit_cast(short8, Afrag[3 + mt * 2]), h1, acc[mt][i], 0, 0, 0);
      }
    }
    __syncthreads();

    float*  qkl = (float*)region;                    // [16][132]
    ushort* vl  = (ushort*)(region + 16 * 132 * 4);  // [64][136]
    #pragma unroll
    for (int i = 0; i < 2; ++i) {
      int px = (w * 2 + i) * 16 + l15;
      #pragma unroll
      for (int r = 0; r < 4; ++r)
        qkl[(l4 * 4 + r) * 132 + px] = acc[0][i][r];
      #pragma unroll
      for (int mt = 1; mt < 5; ++mt)
        #pragma unroll
        for (int r = 0; r < 4; ++r)
          vl[((mt - 1) * 16 + l4 * 4 + r) * 136 + px] = f2bf(acc[mt][i][r]);
    }
    __syncthreads();

    if (t < 128) {
      // Q/K split bf16 (verified): Q=[qh][ql], K=[kh][kl], stride 256.
      int l = t >> 4, tcc = t & 15;
      size_t lrow = (size_t)b * 1024 + lc + l;
      int px = tcc * 8 + l;

      union { ushort s[8]; uint4 v; } qh, ql, kh, kl;
      #pragma unroll
      for (int o = 0; o < 8; ++o) {
        float qv = qkl[o * 132 + px];
        ushort h = f2bf(qv);
        qh.s[o] = h; ql.s[o] = f2bf(qv - bf2f(h));
        float kv = qkl[(8 + o) * 132 + px];
        h = f2bf(kv);
        kh.s[o] = h; kl.s[o] = f2bf(kv - bf2f(h));
      }
      ushort* qrow = Qt2 + lrow * 256 + tcc * 8;
      *(uint4*)qrow         = qh.v;
      *(uint4*)(qrow + 128) = ql.v;
      ushort* krow = Kt2 + lrow * 256 + tcc * 8;
      *(uint4*)krow         = kh.v;
      *(uint4*)(krow + 128) = kl.v;
    } else {
      // V rows (verified path), run CONCURRENTLY with Q/K on waves 2-3.
      int t2 = t - 128;
      int l = t2 >> 4, tcc = t2 & 15;
      size_t lrow = (size_t)b * 1024 + lc + l;

      ushort* vrow = Vt + lrow * 1024;
      #pragma unroll
      for (int it = 0; it < 4; ++it) {
        int c2 = (it << 4) + tcc;
        union { ushort s[16]; uint4 q[2]; } ov;
        #pragma unroll
        for (int tt = 0; tt < 16; ++tt)
          ov.s[tt] = vl[c2 * 136 + tt * 8 + l];
        *(uint4*)(vrow + c2 * 16)     = ov.q[0];
        *(uint4*)(vrow + c2 * 16 + 8) = ov.q[1];
      }
    }
  };

  do_chunk(smem, l0);
  do_chunk(smem + 32768, l0 + 8);
}

// ---------------- Kernel 2: gemm1 = S scores, 128x256 co-resident ------------
// S[i][j] = qh_i.kh_j + ql_i.kh_j + qh_i.kl_j over 6 (KA,KB) tiles.
// R22/R24-validated pattern: BM=128 BN=256 BK=64, 8 waves,
// acc[4][4], 48KB single-buffer LDS, __syncthreads sync, (512,4).
__global__ __launch_bounds__(512, 4) void gemm_qk2(
    const ushort* __restrict__ A,
    const ushort* __restrict__ B,
    float* __restrict__ C)
{
  __shared__ ushort Asm[8192];    // [128][64]
  __shared__ ushort Bsm[16384];   // [256][64]
  int t = threadIdx.x;

  // bijective XCD-chunk remap: 512 blocks, 64 per XCD = 2 batches
  int g = blockIdx.x;
  int lin = (g & 7) * 64 + (g >> 3);
  int bz = lin >> 5;
  int r5 = lin & 31;
  int by = r5 >> 2;              // 0..7, M-tile of 128
  int bx = r5 & 3;               // 0..3, N-tile of 256
  int m0 = by << 7, n0 = bx << 8;

  const ushort* Ab = A + (size_t)bz * 1024 * 256;
  const ushort* Bb = B + (size_t)bz * 1024 * 256;
  int w = t >> 6, lane = t & 63;
  int wm = w >> 2, wn = w & 3;
  int l15 = lane & 15, l4 = lane >> 4;

  int swc = (t & 7) ^ ((t >> 3) & 7);
  const ushort* pa = Ab + (size_t)(m0 + (t >> 3)) * 256 + swc * 8;
  const ushort* pb = Bb + (size_t)(n0 + (t >> 3)) * 256 + swc * 8;
  int wb = w * 512;

  constexpr int KA[6] = {0, 64, 128, 192, 0, 64};
  constexpr int KB[6] = {0, 64, 0, 64, 128, 192};

  f32x4 acc[4][4] = {};

  for (int it = 0; it < 6; ++it) {
    #pragma unroll
    for (int i = 0; i < 2; ++i)      // A: 128 rows (t>>3, +64)
      gload16(pa + (size_t)i * 64 * 256 + KA[it], Asm + i * 4096 + wb);
    #pragma unroll
    for (int i = 0; i < 4; ++i)      // B: 256 rows
      gload16(pb + (size_t)i * 64 * 256 + KB[it], Bsm + i * 4096 + wb);
    __syncthreads();                 // drain vmcnt + barrier (m97 pattern)

    #pragma unroll
    for (int kk = 0; kk < 2; ++kk) {
      short8 af[4], bfr[4];
      #pragma unroll
      for (int mi = 0; mi < 4; ++mi) {
        int rr = (wm << 6) + (mi << 4) + l15;
        af[mi] = __builtin_bit_cast(short8,
            ((const uint4*)Asm)[rr * 8 + ((kk * 4 + l4) ^ (rr & 7))]);
      }
      #pragma unroll
      for (int ni = 0; ni < 4; ++ni) {
        int rr = (wn << 6) + (ni << 4) + l15;
        bfr[ni] = __builtin_bit_cast(short8,
            ((const uint4*)Bsm)[rr * 8 + ((kk * 4 + l4) ^ (rr & 7))]);
      }
      #pragma unroll
      for (int mi = 0; mi < 4; ++mi)
        #pragma unroll
        for (int ni = 0; ni < 4; ++ni)
          acc[mi][ni] = __builtin_amdgcn_mfma_f32_16x16x32_bf16(
              af[mi], bfr[ni], acc[mi][ni], 0, 0, 0);
    }
    __syncthreads();                 // all reads done before next overwrite
  }

  #pragma unroll
  for (int mi = 0; mi < 4; ++mi) {
    int rbase = m0 + (wm << 6) + (mi << 4) + (l4 << 2);
    #pragma unroll
    for (int ni = 0; ni < 4; ++ni) {
      int col = n0 + (wn << 6) + (ni << 4) + l15;
      f32x4 v = acc[mi][ni];
      #pragma unroll
      for (int rr = 0; rr < 4; ++rr) {
        size_t idx = ((size_t)bz * 1024 + rbase + rr) * 1024 + col;
        C[idx] = v[rr];
      }
    }
  }
}

// ---------------- Kernel 4: gemm2, 128x256 tile, 2 blocks/CU (R22-verified) --
__global__ __launch_bounds__(512, 4) void gemm_pv(
    const ushort* __restrict__ A, int lda,
    const ushort* __restrict__ B, int ldb,
    float* __restrict__ C, const float* __restrict__ X)
{
  __shared__ ushort Asm[8192];    // [128][64]
  __shared__ ushort Bsm[16384];   // [256][64]
  int t = threadIdx.x;

  // bijective XCD-chunk remap: 512 blocks, 64 per XCD = 2 batches
  int g = blockIdx.x;
  int lin = (g & 7) * 64 + (g >> 3);
  int bz = lin >> 5;
  int r5 = lin & 31;
  int by = r5 >> 2;              // 0..7, M-tile of 128
  int bx = r5 & 3;               // 0..3, N-tile of 256
  int m0 = by << 7, n0 = bx << 8;

  const ushort* Ab = A + (size_t)bz * 1024 * lda;
  const ushort* Bb = B + (size_t)bz * 1024 * ldb;
  int w = t >> 6, lane = t & 63;
  int wm = w >> 2, wn = w & 3;   // wm: 2 x 64 rows, wn: 4 x 64 cols
  int l15 = lane & 15, l4 = lane >> 4;

  int swc = (t & 7) ^ ((t >> 3) & 7);
  const ushort* pa = Ab + (size_t)(m0 + (t >> 3)) * lda + swc * 8;
  const ushort* pb = Bb + (size_t)(n0 + (t >> 3)) * ldb + swc * 8;
  int wb = w * 512;

  f32x4 acc[4][4] = {};

  for (int it = 0; it < 16; ++it) {
    int k0 = it * 64;
    #pragma unroll
    for (int i = 0; i < 2; ++i)      // A: 128 rows (t>>3, +64)
      gload16(pa + (size_t)i * 64 * lda + k0, Asm + i * 4096 + wb);
    #pragma unroll
    for (int i = 0; i < 4; ++i)      // B: 256 rows
      gload16(pb + (size_t)i * 64 * ldb + k0, Bsm + i * 4096 + wb);
    __syncthreads();                 // drain vmcnt + barrier (m97 pattern)

    #pragma unroll
    for (int kk = 0; kk < 2; ++kk) {
      short8 af[4], bfr[4];
      #pragma unroll
      for (int mi = 0; mi < 4; ++mi) {
        int rr = (wm << 6) + (mi << 4) + l15;
        af[mi] = __builtin_bit_cast(short8,
            ((const uint4*)Asm)[rr * 8 + ((kk * 4 + l4) ^ (rr & 7))]);
      }
      #pragma unroll
      for (int ni = 0; ni < 4; ++ni) {
        int rr = (wn << 6) + (ni << 4) + l15;
        bfr[ni] = __builtin_bit_cast(short8,
            ((const uint4*)Bsm)[rr * 8 + ((kk * 4 + l4) ^ (rr & 7))]);
      }
      #pragma unroll
      for (int mi = 0; mi < 4; ++mi)
        #pragma unroll
        for (int ni = 0; ni < 4; ++ni)
          acc[mi][ni] = __builtin_amdgcn_mfma_f32_16x16x32_bf16(
              af[mi], bfr[ni], acc[mi][ni], 0, 0, 0);
    }
    __syncthreads();                 // all reads done before next overwrite
  }

  #pragma unroll
  for (int mi = 0; mi < 4; ++mi) {
    int rbase = m0 + (wm << 6) + (mi << 4) + (l4 << 2);
    #pragma unroll
    for (int ni = 0; ni < 4; ++ni) {
      int col = n0 + (wn << 6) + (ni << 4) + l15;
      f32x4 v = acc[mi][ni];
      #pragma unroll
      for (int rr = 0; rr < 4; ++rr) {
        size_t idx = ((size_t)bz * 1024 + rbase + rr) * 1024 + col;
        C[idx] = v[rr] + X[idx];
      }
    }
  }
}

// ---------------- Kernel 3: row softmax, P bf16 in place ---------------------
__global__ __launch_bounds__(256) void softmax_rows(float* __restrict__ S)
{
  size_t rowi = blockIdx.x;
  float* srow = S + rowi * 1024;
  int t = threadIdx.x;
  float4 v = ((const float4*)srow)[t];
  float m = fmaxf(fmaxf(v.x, v.y), fmaxf(v.z, v.w));
  #pragma unroll
  for (int off = 32; off > 0; off >>= 1) m = fmaxf(m, __shfl_xor(m, off));
  __shared__ float red[8];
  int wid = t >> 6, lane = t & 63;
  if (lane == 0) red[wid] = m;
  __syncthreads();
  m = fmaxf(fmaxf(red[0], red[1]), fmaxf(red[2], red[3]));
  float e0 = __expf(v.x - m), e1 = __expf(v.y - m);
  float e2 = __expf(v.z - m), e3 = __expf(v.w - m);
  float s = e0 + e1 + e2 + e3;
  #pragma unroll
  for (int off = 32; off > 0; off >>= 1) s += __shfl_xor(s, off);
  if (lane == 0) red[4 + wid] = s;
  __syncthreads();
  s = red[4] + red[5] + red[6] + red[7];
  float inv = 1.0f / s;
  union { ushort h[4]; uint2 q; } pk;
  pk.h[0] = f2bf(e0 * inv); pk.h[1] = f2bf(e1 * inv);
  pk.h[2] = f2bf(e2 * inv); pk.h[3] = f2bf(e3 * inv);
  ((uint2*)srow)[t] = pk.q;
}

// ---------------- Launch -----------------------------------------------------
extern "C" void kernel_launch(void* const* d_in, const int* in_sizes, int n_in,
                              void* d_out, int out_size, void* d_ws, size_t ws_size,
                              hipStream_t stream) {
  const float* x  = (const float*)d_in[0];
  const float* Wq = (const float*)d_in[1];
  const float* bq = (const float*)d_in[2];
  const float* Wk = (const float*)d_in[3];
  const float* bk = (const float*)d_in[4];
  const float* Wv = (const float*)d_in[5];
  const float* bv = (const float*)d_in[6];
  float* out = (float*)d_out;

  char* wsb = (char*)d_ws;
  ushort* Qt2 = (ushort*)wsb;                          //  8,388,608 B
  ushort* Kt2 = (ushort*)(wsb + 8388608);              //  8,388,608 B
  ushort* Vt  = (ushort*)(wsb + 16777216);             // 33,554,432 B
  float*  S   = (float*)(wsb + 50331648);              // 67,108,864 B
  ushort* Wpk = (ushort*)(wsb + 117440512);            // past S (persistent)
  float*  bpk = (float*)(wsb + 117440512 + 24576);

  prep_w2<<<49, 256, 0, stream>>>(Wq, bq, Wk, bk, Wv, bv, Wpk, bpk);
  proj12<<<1024, 256, 0, stream>>>(x, Wpk, bpk, Qt2, Kt2, Vt);
  gemm_qk2<<<512, 512, 0, stream>>>(Qt2, Kt2, S);
  softmax_rows<<<16384, 256, 0, stream>>>(S);
  gemm_pv<<<512, 512, 0, stream>>>((const ushort*)S, 2048, Vt, 1024, out, x);
}